// Round 12
// baseline (1330.466 us; speedup 1.0000x reference)
//
#include <hip/hip_runtime.h>
#include <hip/hip_fp8.h>
#include <cmath>
#include <cstdint>

#define M_TOTAL 4096
#define K_DIM   2048
#define V_DIM   50257
#define V_PAD   50432            /* 197*256, zero-padded rows in quantized W */
#define NVB     197              /* vocab blocks of 256 */
#define NKB     (K_DIM / 32)     /* 64 MX scale blocks per row */
#define BK      128              /* K per mfma_scale_16x16x128 */
#define NKT     (K_DIM / BK)     /* 16 */
#define NWG     (NVB * 16)       /* 3152; 3152/8 = 394 exact */
#define IGNORE_IDX (-100)
#define Z_REG 1e-4f

typedef int    i32x4 __attribute__((ext_vector_type(4)));
typedef int    i32x8 __attribute__((ext_vector_type(8)));
typedef float  f32x4 __attribute__((ext_vector_type(4)));
typedef __bf16 bf16_t;
typedef bf16_t bf16x4 __attribute__((ext_vector_type(4)));
typedef bf16_t bf16x8 __attribute__((ext_vector_type(8)));

typedef const __attribute__((address_space(1))) void g_cvoid;
typedef __attribute__((address_space(3))) void l_void;

__device__ __forceinline__ void gll16(const void* g, void* l) {
    __builtin_amdgcn_global_load_lds((g_cvoid*)(uintptr_t)g,
                                     (l_void*)(uint32_t)(uintptr_t)l, 16, 0, 0);
}

// ---------------- fp32 -> MX fp8-e4m3 quantize (clip-free scale) -----------
__global__ __launch_bounds__(256)
void cvt_f32_fp8mx(const float* __restrict__ src, uint8_t* __restrict__ dq,
                   uint8_t* __restrict__ sT, int rows_valid, int rows_pad)
{
    const long long nthread = (long long)rows_pad * NKB * 8;
    const long long stride  = (long long)gridDim.x * 256;
    for (long long g = (long long)blockIdx.x * 256 + threadIdx.x; g < nthread;
         g += stride) {
        const long long blk = g >> 3;
        const int sub = (int)(g & 7);
        const int row = (int)(blk >> 6);
        const int kb  = (int)(blk & 63);
        f32x4 v = {0.f, 0.f, 0.f, 0.f};
        if (row < rows_valid)
            v = *(const f32x4*)(src + (size_t)row * K_DIM + kb * 32 + sub * 4);
        float m = fmaxf(fmaxf(fabsf(v.x), fabsf(v.y)),
                        fmaxf(fabsf(v.z), fabsf(v.w)));
        m = fmaxf(m, __shfl_xor(m, 1, 64));
        m = fmaxf(m, __shfl_xor(m, 2, 64));
        m = fmaxf(m, __shfl_xor(m, 4, 64));
        const int eb = (int)((__float_as_uint(m) >> 23) & 0xff);
        uint32_t wq = 0u;
        int sbyte = 0;
        if (eb != 0) {
            int E = min(max(eb - 135, -126), 119);
            float mult = __uint_as_float((uint32_t)(127 - E) << 23);
            if (m * mult > 448.f) { E += 1; mult *= 0.5f; }
            sbyte = E + 127;
            const float q0 = fminf(fmaxf(v.x * mult, -448.f), 448.f);
            const float q1 = fminf(fmaxf(v.y * mult, -448.f), 448.f);
            const float q2 = fminf(fmaxf(v.z * mult, -448.f), 448.f);
            const float q3 = fminf(fmaxf(v.w * mult, -448.f), 448.f);
            const __hip_fp8_e4m3 f0(q0), f1(q1), f2(q2), f3(q3);
            wq = (uint32_t)f0.__x | ((uint32_t)f1.__x << 8)
               | ((uint32_t)f2.__x << 16) | ((uint32_t)f3.__x << 24);
        }
        ((uint32_t*)dq)[blk * 8 + sub] = wq;
        if (sub == 0) sT[(size_t)kb * rows_pad + row] = (uint8_t)sbyte;
    }
}

// ---------------- fused MX-fp8 GEMM + online softmax stats -----------------
// Round-9 shell (256x256 tile, 8 waves 2m x 4v, m-inner-16, XCD swizzle,
// 16x16x128 MFMA, B-staging + swizzle verbatim) with:
//   * A fragments loaded DIRECTLY global->VGPR (A is 8MB, L3-resident) —
//     LDS reads cut 24 -> 8 b128/lane/tile (conflicts are structural:
//     8 slots per 128B row can't serve 32 lanes uniquely, r9/r11 both 3.9e7)
//   * LDS = B dbuf 64KB + B-scale dbuf 2KB -> 2 blocks/CU (m114/m148
//     overlap: co-resident blocks fill each other's drain/LDS bubbles)
//   * B scales staged via gll16 (wave 0) + ds_read_u8 (was uncoalesced
//     global byte loads)
__global__ __launch_bounds__(512, 2)
void lce_gemm_fp8(const uint8_t* __restrict__ Xq, const uint8_t* __restrict__ Wq,
                  const uint8_t* __restrict__ sAT, const uint8_t* __restrict__ sBT,
                  float* __restrict__ pm, float* __restrict__ ps)
{
    __shared__ __align__(16) uint8_t Bs[2][256 * BK];   // 2 x 32KB (B data)
    __shared__ __align__(16) uint8_t Ss[2][1024];       // 2 x 1KB  (B scales)

    const int bid = blockIdx.x;
    const int wg  = (bid & 7) * (NWG / 8) + (bid >> 3);  // XCD swizzle
    const int vb  = wg >> 4;       // m-inner: 16 consecutive wgs share W panel
    const int mb  = wg & 15;
    const int m0  = mb * 256;
    const int v0  = vb * 256;

    const int tid  = threadIdx.x;
    const int lane = tid & 63;
    const int wave = tid >> 6;
    const int wr   = wave >> 2;    // 2(m) x 4(v); per-wave 128x64 out
    const int wc   = wave & 3;
    const int lo4  = lane & 15;
    const int hi2  = lane >> 4;
    const int sw   = lo4 & 7;      // B read-side XOR term (row&7)

    // ---- B staging (r9 verbatim): lane l -> LDS (row8 l>>3, slot l&7),
    // global col slot inverse-swizzled (l&7)^(l>>3)
    const int l7 = lane & 7, l3 = lane >> 3;
    const int scol = ((l7 ^ l3) << 4);
    const uint8_t* baseB = Wq + (size_t)(v0 + wave * 8 + l3) * K_DIM + scol;
    char* ldsB_w = (char*)&Bs[0][0] + wave * 1024;

    // ---- B-scale staging source (wave 0): kblk t*4+(l>>4), rows v0+(l&15)*16
    const uint8_t* baseSB = sBT + (size_t)(lane >> 4) * V_PAD + v0 + (lane & 15) * 16;

    // ---- A direct-from-global: row m0+wr*128+m*16+lo4, K byte t*128+hi2*32
    const uint8_t* aBase  = Xq + (size_t)(m0 + wr * 128 + lo4) * K_DIM + hi2 * 32;
    const uint8_t* saBase = sAT + (size_t)hi2 * M_TOTAL + m0 + wr * 128 + lo4;

#define STAGE_B(tt) do { const int _b = ((tt) & 1) * 32768;                   \
        const size_t _k = (size_t)(tt) * BK;                                  \
        _Pragma("unroll")                                                     \
        for (int u = 0; u < 4; ++u)                                           \
            gll16(baseB + (size_t)u * 64 * K_DIM + _k, ldsB_w + _b + u * 8192);\
        if (wave == 0)                                                        \
            gll16(baseSB + (size_t)(tt) * 4 * V_PAD, &Ss[(tt) & 1][0]);       \
    } while (0)

    // read lane's 32B B fragment: rows rowbase+lo4, slots 2*hi2, 2*hi2+1
#define RD8(dst_, base_, rowbase_) do {                                       \
        const char* _p = (base_) + ((rowbase_) + lo4) * 128;                  \
        const i32x4 _lo = *(const i32x4*)(_p + (((hi2 << 1) | 0) ^ sw) * 16); \
        const i32x4 _hi = *(const i32x4*)(_p + (((hi2 << 1) | 1) ^ sw) * 16); \
        dst_[0] = _lo[0]; dst_[1] = _lo[1]; dst_[2] = _lo[2]; dst_[3] = _lo[3];\
        dst_[4] = _hi[0]; dst_[5] = _hi[1]; dst_[6] = _hi[2]; dst_[7] = _hi[3];\
    } while (0)

    f32x4 acc[8][4];
    #pragma unroll
    for (int m = 0; m < 8; ++m)
        #pragma unroll
        for (int n = 0; n < 4; ++n) {
            f32x4 z = {0.f, 0.f, 0.f, 0.f};
            acc[m][n] = z;
        }

    STAGE_B(0);
    asm volatile("s_waitcnt vmcnt(0)" ::: "memory");
    __builtin_amdgcn_s_barrier();

    for (int t = 0; t < NKT; ++t) {
        const char*    Bb   = (const char*)&Bs[0][0] + (t & 1) * 32768;
        const uint8_t* sLds = &Ss[t & 1][0];
        if (t + 1 < NKT) STAGE_B(t + 1);   // lands under this tile's work

        // B frags + B scales (LDS)
        i32x8 bf[4];  int sb[4];
        #pragma unroll
        for (int n = 0; n < 4; ++n) {
            RD8(bf[n], Bb, wc * 64 + n * 16);
            sb[n] = sLds[hi2 * 256 + wc * 64 + n * 16 + lo4];
        }

        // A frags direct from global (L3-resident), scales likewise
        const uint8_t* aT  = aBase  + t * 128;
        const uint8_t* saT = saBase + (size_t)t * 4 * M_TOTAL;

        __builtin_amdgcn_s_setprio(1);
        #pragma unroll
        for (int m = 0; m < 8; ++m) {
            const char* ap = (const char*)(aT + (size_t)m * 16 * K_DIM);
            const i32x4 alo = *(const i32x4*)(ap);
            const i32x4 ahi = *(const i32x4*)(ap + 16);
            i32x8 af;
            af[0] = alo[0]; af[1] = alo[1]; af[2] = alo[2]; af[3] = alo[3];
            af[4] = ahi[0]; af[5] = ahi[1]; af[6] = ahi[2]; af[7] = ahi[3];
            const int sa = saT[(size_t)m * 16];
            #pragma unroll
            for (int n = 0; n < 4; ++n)
                acc[m][n] = __builtin_amdgcn_mfma_scale_f32_16x16x128_f8f6f4(
                    af, bf[n], acc[m][n], 0, 0, 0, sa, 0, sb[n]);
        }
        __builtin_amdgcn_s_setprio(0);

        asm volatile("s_waitcnt vmcnt(0)" ::: "memory");
        __builtin_amdgcn_s_barrier();
    }
#undef STAGE_B
#undef RD8

    // ---- epilogue: per-row max/sumexp over this block's 256 cols ----------
    // C layout (m89, shape-determined): col = lane&15, row = (lane>>4)*4 + reg
    float* scrM = (float*)&Bs[0][0];        // [256][4] wc-partials
    float* scrS = scrM + 1024;
    #pragma unroll
    for (int m = 0; m < 8; ++m) {
        #pragma unroll
        for (int j = 0; j < 4; ++j) {
            float v_[4];
            float vmax = -INFINITY;
            #pragma unroll
            for (int n = 0; n < 4; ++n) {
                const int gcol = v0 + wc * 64 + n * 16 + lo4;
                const float v  = acc[m][n][j];
                v_[n] = (gcol < V_DIM) ? v : -INFINITY;
                vmax = fmaxf(vmax, v_[n]);
            }
            #pragma unroll
            for (int d = 1; d < 16; d <<= 1)
                vmax = fmaxf(vmax, __shfl_xor(vmax, d, 64));
            float s = 0.f;
            if (vmax > -INFINITY) {
                #pragma unroll
                for (int n = 0; n < 4; ++n) s += __expf(v_[n] - vmax);
                #pragma unroll
                for (int d = 1; d < 16; d <<= 1)
                    s += __shfl_xor(s, d, 64);
            }
            if (lo4 == 0) {
                const int row = wr * 128 + m * 16 + hi2 * 4 + j;
                scrM[row * 4 + wc] = vmax;
                scrS[row * 4 + wc] = s;
            }
        }
    }
    __syncthreads();
    if (tid < 256) {
        float M = -INFINITY;
        #pragma unroll
        for (int w4 = 0; w4 < 4; ++w4) M = fmaxf(M, scrM[tid * 4 + w4]);
        float S = 0.f;
        #pragma unroll
        for (int w4 = 0; w4 < 4; ++w4) {
            const float mm = scrM[tid * 4 + w4];
            if (mm > -INFINITY) S += scrS[tid * 4 + w4] * __expf(mm - M);
        }
        const size_t idx = (size_t)vb * M_TOTAL + m0 + tid;
        pm[idx] = M;
        ps[idx] = S;
    }
}

// ---------------- picked logit from EXACT fp32 inputs ----------------------
__global__ __launch_bounds__(256)
void lce_picked_f32(const float* __restrict__ x, const float* __restrict__ w,
                    const int* __restrict__ labels, float* __restrict__ picked)
{
    const int wv  = threadIdx.x >> 6, ln = threadIdx.x & 63;
    const int row = blockIdx.x * 4 + wv;
    const int lbl = labels[row];
    float s = 0.f;
    if (lbl != IGNORE_IDX) {
        const float* xr = x + (size_t)row * K_DIM;
        const float* wr = w + (size_t)lbl * K_DIM;
        #pragma unroll
        for (int c = 0; c < 8; ++c) {
            const f32x4 a = *(const f32x4*)(xr + c * 256 + ln * 4);
            const f32x4 b = *(const f32x4*)(wr + c * 256 + ln * 4);
            s += a.x * b.x + a.y * b.y + a.z * b.z + a.w * b.w;
        }
    }
    #pragma unroll
    for (int d = 32; d; d >>= 1) s += __shfl_down(s, d, 64);
    if (ln == 0) picked[row] = s;
}

// ---------------- chunk-combine + finalize ---------------------------------
__global__ __launch_bounds__(256)
void lce_row_reduce(const float* __restrict__ pm, const float* __restrict__ ps,
                    const float* __restrict__ picked, const int* __restrict__ labels,
                    float* __restrict__ pb)
{
    const int r   = blockIdx.x * 256 + threadIdx.x;
    const int lbl = labels[r];
    float nll = 0.f, zsq = 0.f, val = 0.f;
    if (lbl != IGNORE_IDX) {
        float M = -INFINITY;
        for (int c = 0; c < NVB; ++c)
            M = fmaxf(M, pm[(size_t)c * M_TOTAL + r]);
        float S = 0.f;
        for (int c = 0; c < NVB; ++c) {
            const float mc = pm[(size_t)c * M_TOTAL + r];
            if (mc > -INFINITY) S += ps[(size_t)c * M_TOTAL + r] * expf(mc - M);
        }
        const float lse = M + logf(S);
        nll = lse - picked[r];
        zsq = lse * lse;
        val = 1.f;
    }
    #pragma unroll
    for (int d = 32; d; d >>= 1) {
        nll += __shfl_down(nll, d, 64);
        zsq += __shfl_down(zsq, d, 64);
        val += __shfl_down(val, d, 64);
    }
    __shared__ float red[3][4];
    const int wv = threadIdx.x >> 6, ln = threadIdx.x & 63;
    if (ln == 0) { red[0][wv] = nll; red[1][wv] = zsq; red[2][wv] = val; }
    __syncthreads();
    if (threadIdx.x == 0) {
        float a = 0.f, b = 0.f, c_ = 0.f;
        #pragma unroll
        for (int i = 0; i < 4; ++i) { a += red[0][i]; b += red[1][i]; c_ += red[2][i]; }
        pb[blockIdx.x * 3 + 0] = a;
        pb[blockIdx.x * 3 + 1] = b;
        pb[blockIdx.x * 3 + 2] = c_;
    }
}

__global__ void lce_finalize(const float* __restrict__ pb, float* __restrict__ out)
{
    float a = 0.f, b = 0.f, c_ = 0.f;
    for (int i = 0; i < 16; ++i) {
        a  += pb[i * 3 + 0];
        b  += pb[i * 3 + 1];
        c_ += pb[i * 3 + 2];
    }
    const float denom = fmaxf(c_, 1.f);
    float loss = a / denom;
    if (c_ > 0.f) loss += Z_REG * (b / denom);
    out[0] = loss;
}

// ---------------- fallback fused fp32 path (round-0 kernel, tiny ws) -------
#define FVC 1024
#define FNCHUNK 50
#define FBK 64
#define LDSPAD 72
__device__ inline bf16x4 cvt4(f32x4 v) {
    bf16x4 r;
    r.x = (bf16_t)v.x; r.y = (bf16_t)v.y; r.z = (bf16_t)v.z; r.w = (bf16_t)v.w;
    return r;
}
__global__ __launch_bounds__(256)
void lce_gemm_stats_fused(const float* __restrict__ X, const float* __restrict__ W,
                          const int* __restrict__ labels,
                          float* __restrict__ pm, float* __restrict__ ps,
                          float* __restrict__ pp)
{
    __shared__ bf16_t As[128][LDSPAD];
    __shared__ bf16_t Bsh[128][LDSPAD];
    __shared__ float  sm[128], ss[128], sp[128];
    __shared__ float  part_m[2][128], part_s[2][128];
    __shared__ int    slab[128];

    const int bx    = blockIdx.x;
    const int chunk = bx >> 5;
    const int mb    = bx & 31;
    const int m0    = mb * 128;
    const int v0    = chunk * FVC;
    const int tid   = threadIdx.x;
    const int lane  = tid & 63;
    const int wave  = tid >> 6;
    const int wr    = wave >> 1;
    const int wc    = wave & 1;
    const int lo4   = lane & 15;
    const int hi2   = lane >> 4;
    const int sr0   = tid >> 4;
    const int sc4   = tid & 15;

    if (tid < 128) {
        sm[tid] = -INFINITY; ss[tid] = 0.f; sp[tid] = 0.f;
        slab[tid] = labels[m0 + tid];
    }
    __syncthreads();

    const int ncols = min(FVC, V_DIM - v0);
    const int nt    = (ncols + 127) >> 7;

    for (int vt = 0; vt < nt; ++vt) {
        f32x4 acc[4][4];
        #pragma unroll
        for (int m = 0; m < 4; ++m)
            #pragma unroll
            for (int n = 0; n < 4; ++n) {
                f32x4 z = {0.f, 0.f, 0.f, 0.f};
                acc[m][n] = z;
            }
        const int vrow0 = v0 + vt * 128;
        for (int kt = 0; kt < K_DIM / FBK; ++kt) {
            #pragma unroll
            for (int i = 0; i < 8; ++i) {
                const int row = i * 16 + sr0;
                const f32x4 va = *(const f32x4*)(X + (size_t)(m0 + row) * K_DIM + kt * FBK + sc4 * 4);
                *(bf16x4*)&As[row][sc4 * 4] = cvt4(va);
                const int grow = vrow0 + row;
                f32x4 vb = {0.f, 0.f, 0.f, 0.f};
                if (grow < V_DIM)
                    vb = *(const f32x4*)(W + (size_t)grow * K_DIM + kt * FBK + sc4 * 4);
                *(bf16x4*)&Bsh[row][sc4 * 4] = cvt4(vb);
            }
            __syncthreads();
            #pragma unroll
            for (int ks = 0; ks < 2; ++ks) {
                bf16x8 af[4], bfr[4];
                #pragma unroll
                for (int m = 0; m < 4; ++m)
                    af[m] = *(const bf16x8*)&As[wr * 64 + m * 16 + lo4][ks * 32 + hi2 * 8];
                #pragma unroll
                for (int n = 0; n < 4; ++n)
                    bfr[n] = *(const bf16x8*)&Bsh[wc * 64 + n * 16 + lo4][ks * 32 + hi2 * 8];
                #pragma unroll
                for (int m = 0; m < 4; ++m)
                    #pragma unroll
                    for (int n = 0; n < 4; ++n)
                        acc[m][n] = __builtin_amdgcn_mfma_f32_16x16x32_bf16(af[m], bfr[n], acc[m][n], 0, 0, 0);
            }
            __syncthreads();
        }
        const int vbase = vrow0 + wc * 64;
        #pragma unroll
        for (int m = 0; m < 4; ++m) {
            #pragma unroll
            for (int j = 0; j < 4; ++j) {
                const int rloc = wr * 64 + m * 16 + hi2 * 4 + j;
                const int lb   = slab[rloc];
                float vmax = -INFINITY;
                float v_[4];
                #pragma unroll
                for (int n = 0; n < 4; ++n) {
                    const int gcol = vbase + n * 16 + lo4;
                    const float v  = acc[m][n][j];
                    const bool ok  = (gcol < V_DIM);
                    v_[n] = ok ? v : -INFINITY;
                    if (ok && gcol == lb) sp[rloc] = v;
                    vmax = fmaxf(vmax, v_[n]);
                }
                #pragma unroll
                for (int d = 1; d < 16; d <<= 1)
                    vmax = fmaxf(vmax, __shfl_xor(vmax, d, 64));
                float s = 0.f;
                #pragma unroll
                for (int n = 0; n < 4; ++n) s += __expf(v_[n] - vmax);
                #pragma unroll
                for (int d = 1; d < 16; d <<= 1) s += __shfl_xor(s, d, 64);
                if (lo4 == 0) { part_m[wc][rloc] = vmax; part_s[wc][rloc] = s; }
            }
        }
        __syncthreads();
        if (tid < 128) {
            const float om  = sm[tid], os = ss[tid];
            const float m0_ = part_m[0][tid], s0 = part_s[0][tid];
            const float m1_ = part_m[1][tid], s1 = part_s[1][tid];
            const float nm  = fmaxf(om, fmaxf(m0_, m1_));
            float ns = 0.f;
            if (om  > -INFINITY) ns += os * __expf(om  - nm);
            if (m0_ > -INFINITY) ns += s0 * __expf(m0_ - nm);
            if (m1_ > -INFINITY) ns += s1 * __expf(m1_ - nm);
            sm[tid] = nm; ss[tid] = ns;
        }
    }
    __syncthreads();
    if (tid < 128) {
        const size_t idx = (size_t)chunk * M_TOTAL + (m0 + tid);
        pm[idx] = sm[tid]; ps[idx] = ss[tid]; pp[idx] = sp[tid];
    }
}

__global__ __launch_bounds__(256)
void lce_row_reduce_f(const float* __restrict__ pm, const float* __restrict__ ps,
                      const float* __restrict__ pp, const int* __restrict__ labels,
                      float* __restrict__ pb)
{
    const int r   = blockIdx.x * 256 + threadIdx.x;
    const int lbl = labels[r];
    float nll = 0.f, zsq = 0.f, val = 0.f;
    if (lbl != IGNORE_IDX) {
        float M = -INFINITY;
        for (int c = 0; c < FNCHUNK; ++c)
            M = fmaxf(M, pm[(size_t)c * M_TOTAL + r]);
        float S = 0.f, P = 0.f;
        for (int c = 0; c < FNCHUNK; ++c) {
            const float mc = pm[(size_t)c * M_TOTAL + r];
            if (mc > -INFINITY) S += ps[(size_t)c * M_TOTAL + r] * expf(mc - M);
            P += pp[(size_t)c * M_TOTAL + r];
        }
        const float lse = M + logf(S);
        nll = lse - P; zsq = lse * lse; val = 1.f;
    }
    #pragma unroll
    for (int d = 32; d; d >>= 1) {
        nll += __shfl_down(nll, d, 64);
        zsq += __shfl_down(zsq, d, 64);
        val += __shfl_down(val, d, 64);
    }
    __shared__ float red[3][4];
    const int wv = threadIdx.x >> 6, ln = threadIdx.x & 63;
    if (ln == 0) { red[0][wv] = nll; red[1][wv] = zsq; red[2][wv] = val; }
    __syncthreads();
    if (threadIdx.x == 0) {
        float a = 0.f, b = 0.f, c_ = 0.f;
        #pragma unroll
        for (int i = 0; i < 4; ++i) { a += red[0][i]; b += red[1][i]; c_ += red[2][i]; }
        pb[blockIdx.x * 3 + 0] = a;
        pb[blockIdx.x * 3 + 1] = b;
        pb[blockIdx.x * 3 + 2] = c_;
    }
}

extern "C" void kernel_launch(void* const* d_in, const int* in_sizes, int n_in,
                              void* d_out, int out_size, void* d_ws, size_t ws_size,
                              hipStream_t stream)
{
    const float* x      = (const float*)d_in[0];
    const int*   labels = (const int*)d_in[1];
    const float* w      = (const float*)d_in[2];
    float*       out    = (float*)d_out;

    const size_t wq_b   = (size_t)V_PAD * K_DIM;        // 103,284,736
    const size_t xq_b   = (size_t)M_TOTAL * K_DIM;      //   8,388,608
    const size_t sbt_b  = (size_t)NKB * V_PAD;          //   3,227,648
    const size_t sat_b  = (size_t)NKB * M_TOTAL;        //     262,144
    const size_t stat_n = (size_t)NVB * M_TOTAL;        //     806,912

    size_t off = 0;
    auto take = [&](size_t bytes) { size_t o = off; off += (bytes + 255) & ~(size_t)255; return o; };
    const size_t o_wq  = take(wq_b);
    const size_t o_xq  = take(xq_b);
    const size_t o_sbt = take(sbt_b);
    const size_t o_sat = take(sat_b);
    const size_t o_pm  = take(stat_n * sizeof(float));
    const size_t o_ps  = take(stat_n * sizeof(float));
    const size_t o_pk  = take(M_TOTAL * sizeof(float));
    const size_t o_pb  = take(16 * 3 * sizeof(float));
    const size_t need  = off;

    if (ws_size >= need) {
        uint8_t* Wq  = (uint8_t*)d_ws + o_wq;
        uint8_t* Xq  = (uint8_t*)d_ws + o_xq;
        uint8_t* sBT = (uint8_t*)d_ws + o_sbt;
        uint8_t* sAT = (uint8_t*)d_ws + o_sat;
        float* pm     = (float*)((char*)d_ws + o_pm);
        float* ps     = (float*)((char*)d_ws + o_ps);
        float* picked = (float*)((char*)d_ws + o_pk);
        float* pb     = (float*)((char*)d_ws + o_pb);

        cvt_f32_fp8mx<<<dim3(4096), dim3(256), 0, stream>>>(w, Wq, sBT, V_DIM, V_PAD);
        cvt_f32_fp8mx<<<dim3(1024), dim3(256), 0, stream>>>(x, Xq, sAT, M_TOTAL, M_TOTAL);
        lce_gemm_fp8<<<dim3(NWG), dim3(512), 0, stream>>>(Xq, Wq, sAT, sBT, pm, ps);
        lce_picked_f32<<<dim3(1024), dim3(256), 0, stream>>>(x, w, labels, picked);
        lce_row_reduce<<<dim3(16), dim3(256), 0, stream>>>(pm, ps, picked, labels, pb);
        lce_finalize<<<dim3(1), dim3(1), 0, stream>>>(pb, out);
    } else {
        const size_t fstat_n = (size_t)FNCHUNK * M_TOTAL;
        float* pm = (float*)d_ws;
        float* ps = pm + fstat_n;
        float* pp = ps + fstat_n;
        float* pb = pp + fstat_n;
        lce_gemm_stats_fused<<<dim3(FNCHUNK * 32), dim3(256), 0, stream>>>(
            x, w, labels, pm, ps, pp);
        lce_row_reduce_f<<<dim3(16), dim3(256), 0, stream>>>(pm, ps, pp, labels, pb);
        lce_finalize<<<dim3(1), dim3(1), 0, stream>>>(pb, out);
    }
}

// Round 13
// 816.329 us; speedup vs baseline: 1.6298x; 1.6298x over previous
//
#include <hip/hip_runtime.h>
#include <hip/hip_fp8.h>
#include <cmath>
#include <cstdint>

#define M_TOTAL 4096
#define K_DIM   2048
#define V_DIM   50257
#define V_PAD   50432            /* 197*256, zero-padded rows in quantized W */
#define NVB     197              /* vocab blocks of 256 */
#define NKB     (K_DIM / 32)     /* 64 MX scale blocks per row */
#define BK      128              /* K per mfma_scale_16x16x128 */
#define NKT     (K_DIM / BK)     /* 16 */
#define NWG     (NVB * 16)       /* 3152; 3152/8 = 394 exact */
#define IGNORE_IDX (-100)
#define Z_REG 1e-4f

typedef int    i32x4 __attribute__((ext_vector_type(4)));
typedef int    i32x8 __attribute__((ext_vector_type(8)));
typedef float  f32x4 __attribute__((ext_vector_type(4)));
typedef __bf16 bf16_t;
typedef bf16_t bf16x4 __attribute__((ext_vector_type(4)));
typedef bf16_t bf16x8 __attribute__((ext_vector_type(8)));

typedef const __attribute__((address_space(1))) void g_cvoid;
typedef __attribute__((address_space(3))) void l_void;

__device__ __forceinline__ void gll16(const void* g, void* l) {
    __builtin_amdgcn_global_load_lds((g_cvoid*)(uintptr_t)g,
                                     (l_void*)(uint32_t)(uintptr_t)l, 16, 0, 0);
}

// ---------------- fp32 -> MX fp8-e4m3 quantize (clip-free scale) -----------
// Scale rows PERMUTED within gs-groups so the GEMM's per-lane scale bytes
// are contiguous: row' = (row & ~(G-1)) | (row%16)<<(gs-4) | (row%G)>>4.
// A (X): gs=7 (128-row groups, lane reads u64); B (W): gs=6 (64-row, u32).
template <int GS>
__global__ __launch_bounds__(256)
void cvt_f32_fp8mx(const float* __restrict__ src, uint8_t* __restrict__ dq,
                   uint8_t* __restrict__ sT, int rows_valid, int rows_pad)
{
    const long long nthread = (long long)rows_pad * NKB * 8;
    const long long stride  = (long long)gridDim.x * 256;
    for (long long g = (long long)blockIdx.x * 256 + threadIdx.x; g < nthread;
         g += stride) {
        const long long blk = g >> 3;
        const int sub = (int)(g & 7);
        const int row = (int)(blk >> 6);
        const int kb  = (int)(blk & 63);
        f32x4 v = {0.f, 0.f, 0.f, 0.f};
        if (row < rows_valid)
            v = *(const f32x4*)(src + (size_t)row * K_DIM + kb * 32 + sub * 4);
        float m = fmaxf(fmaxf(fabsf(v.x), fabsf(v.y)),
                        fmaxf(fabsf(v.z), fabsf(v.w)));
        m = fmaxf(m, __shfl_xor(m, 1, 64));
        m = fmaxf(m, __shfl_xor(m, 2, 64));
        m = fmaxf(m, __shfl_xor(m, 4, 64));
        const int eb = (int)((__float_as_uint(m) >> 23) & 0xff);
        uint32_t wq = 0u;
        int sbyte = 0;
        if (eb != 0) {
            int E = min(max(eb - 135, -126), 119);
            float mult = __uint_as_float((uint32_t)(127 - E) << 23);
            if (m * mult > 448.f) { E += 1; mult *= 0.5f; }
            sbyte = E + 127;
            const float q0 = fminf(fmaxf(v.x * mult, -448.f), 448.f);
            const float q1 = fminf(fmaxf(v.y * mult, -448.f), 448.f);
            const float q2 = fminf(fmaxf(v.z * mult, -448.f), 448.f);
            const float q3 = fminf(fmaxf(v.w * mult, -448.f), 448.f);
            const __hip_fp8_e4m3 f0(q0), f1(q1), f2(q2), f3(q3);
            wq = (uint32_t)f0.__x | ((uint32_t)f1.__x << 8)
               | ((uint32_t)f2.__x << 16) | ((uint32_t)f3.__x << 24);
        }
        ((uint32_t*)dq)[blk * 8 + sub] = wq;
        if (sub == 0) {
            const int G = 1 << GS;
            const int rp = (row & ~(G - 1)) | ((row & 15) << (GS - 4))
                         | ((row & (G - 1)) >> 4);
            sT[(size_t)kb * rows_pad + rp] = (uint8_t)sbyte;
        }
    }
}

// ---------------- fused MX-fp8 GEMM + online softmax stats -----------------
// Round-9 structure VERBATIM (best measured: 644us, 1310 TF eff): 256x256
// tile, 8 waves 2m x 4v, m-inner-16 grid + XCD swizzle (FETCH 0.58GB),
// dbuf 2x(32+32)KB LDS, vmcnt(0)+1 barrier per K-tile, 16x16x128 MFMA.
// Delta vs r9: MX scales read as ONE u64 (A) + ONE u32 (B) per lane per
// tile from permuted layout (was 12 strided byte loads); frag vectors
// assembled with shufflevector (no element-copy v_movs).
__global__ __launch_bounds__(512, 2)
void lce_gemm_fp8(const uint8_t* __restrict__ Xq, const uint8_t* __restrict__ Wq,
                  const uint8_t* __restrict__ sAT, const uint8_t* __restrict__ sBT,
                  float* __restrict__ pm, float* __restrict__ ps)
{
    __shared__ __align__(16) uint8_t As[2][256 * BK];   // 2 x 32KB
    __shared__ __align__(16) uint8_t Bs[2][256 * BK];   // 2 x 32KB (128KB)

    const int bid = blockIdx.x;
    const int wg  = (bid & 7) * (NWG / 8) + (bid >> 3);  // XCD swizzle
    const int vb  = wg >> 4;       // m-inner: 16 consecutive wgs share W panel
    const int mb  = wg & 15;
    const int m0  = mb * 256;
    const int v0  = vb * 256;

    const int tid  = threadIdx.x;
    const int lane = tid & 63;
    const int wave = tid >> 6;
    const int wr   = wave >> 2;    // 2(m) x 4(v); per-wave 128x64 out
    const int wc   = wave & 3;
    const int lo4  = lane & 15;
    const int hi2  = lane >> 4;
    const int sw   = lo4 & 7;      // read-side XOR term (row&7)

    // staging (r9 verbatim): lane l -> LDS (row8 l>>3, slot l&7); global
    // col slot inverse-swizzled (l&7)^(l>>3); 1 issue = 1KB = 8 rows
    const int l7 = lane & 7, l3 = lane >> 3;
    const int scol = ((l7 ^ l3) << 4);
    const int srow = wave * 8 + l3;
    const uint8_t* baseA = Xq + (size_t)(m0 + srow) * K_DIM + scol;
    const uint8_t* baseB = Wq + (size_t)(v0 + srow) * K_DIM + scol;
    char* ldsA_w = (char*)&As[0][0] + wave * 1024;
    char* ldsB_w = (char*)&Bs[0][0] + wave * 1024;

    // permuted scale bases: A lane -> u64 at group(m0+wr*128) + lo4*8;
    // B lane -> u32 at group(v0+wc*64) + lo4*4  (kblk = t*4 + hi2)
    const uint8_t* saBase = sAT + (size_t)hi2 * M_TOTAL + m0 + wr * 128 + lo4 * 8;
    const uint8_t* sbBase = sBT + (size_t)hi2 * V_PAD  + v0 + wc * 64  + lo4 * 4;

#define STAGE(tt) do { const int _b = ((tt) & 1) * 32768;                    \
        const size_t _k = (size_t)(tt) * BK;                                 \
        _Pragma("unroll")                                                    \
        for (int u = 0; u < 4; ++u) {                                        \
            gll16(baseA + (size_t)u * 64 * K_DIM + _k, ldsA_w + _b + u * 8192);\
            gll16(baseB + (size_t)u * 64 * K_DIM + _k, ldsB_w + _b + u * 8192);\
        } } while (0)

    // read one 32B/lane operand fragment: rows rowbase+lo4, slots 2*hi2, +1
#define RD8(dst_, base_, rowbase_) do {                                      \
        const char* _p = (base_) + ((rowbase_) + lo4) * 128;                 \
        const i32x4 _lo = *(const i32x4*)(_p + (((hi2 << 1) | 0) ^ sw) * 16);\
        const i32x4 _hi = *(const i32x4*)(_p + (((hi2 << 1) | 1) ^ sw) * 16);\
        dst_ = __builtin_shufflevector(_lo, _hi, 0, 1, 2, 3, 4, 5, 6, 7);    \
    } while (0)

    f32x4 acc[8][4];
    #pragma unroll
    for (int m = 0; m < 8; ++m)
        #pragma unroll
        for (int n = 0; n < 4; ++n) {
            f32x4 z = {0.f, 0.f, 0.f, 0.f};
            acc[m][n] = z;
        }

    STAGE(0);
    asm volatile("s_waitcnt vmcnt(0)" ::: "memory");
    __builtin_amdgcn_s_barrier();

    for (int t = 0; t < NKT; ++t) {
        const char* Ab = (const char*)&As[0][0] + (t & 1) * 32768;
        const char* Bb = (const char*)&Bs[0][0] + (t & 1) * 32768;

        // per-lane MX scales: 2 loads/tile (permuted layout)
        const uint64_t a64 = *(const uint64_t*)(saBase + (size_t)t * 4 * M_TOTAL);
        const uint32_t b32 = *(const uint32_t*)(sbBase + (size_t)t * 4 * V_PAD);

        if (t + 1 < NKT) STAGE(t + 1);   // lands under this tile's work

        i32x8 bf[4];
        #pragma unroll
        for (int n = 0; n < 4; ++n) RD8(bf[n], Bb, wc * 64 + n * 16);
        i32x8 af[4];
        #pragma unroll
        for (int m = 0; m < 4; ++m) RD8(af[m], Ab, wr * 128 + m * 16);

        __builtin_amdgcn_s_setprio(1);
        #pragma unroll
        for (int m = 0; m < 4; ++m) {
            const int sa = (int)((a64 >> (8 * m)) & 0xff);
            #pragma unroll
            for (int n = 0; n < 4; ++n)
                acc[m][n] = __builtin_amdgcn_mfma_scale_f32_16x16x128_f8f6f4(
                    af[m], bf[n], acc[m][n], 0, 0, 0, sa, 0,
                    (int)((b32 >> (8 * n)) & 0xff));
        }
        __builtin_amdgcn_s_setprio(0);

        #pragma unroll
        for (int m = 0; m < 4; ++m) RD8(af[m], Ab, wr * 128 + 64 + m * 16);
        __builtin_amdgcn_s_setprio(1);
        #pragma unroll
        for (int m = 0; m < 4; ++m) {
            const int sa = (int)((a64 >> (8 * (4 + m))) & 0xff);
            #pragma unroll
            for (int n = 0; n < 4; ++n)
                acc[4 + m][n] = __builtin_amdgcn_mfma_scale_f32_16x16x128_f8f6f4(
                    af[m], bf[n], acc[4 + m][n], 0, 0, 0, sa, 0,
                    (int)((b32 >> (8 * n)) & 0xff));
        }
        __builtin_amdgcn_s_setprio(0);

        if (t + 1 < NKT) asm volatile("s_waitcnt vmcnt(0)" ::: "memory");
        __builtin_amdgcn_s_barrier();
    }
#undef STAGE
#undef RD8

    // ---- epilogue: per-row max/sumexp over this block's 256 cols ----------
    // C layout (m89, shape-determined): col = lane&15, row = (lane>>4)*4 + reg
    float* scrM = (float*)&As[0][0];        // [256][4] wc-partials
    float* scrS = scrM + 1024;
    #pragma unroll
    for (int m = 0; m < 8; ++m) {
        #pragma unroll
        for (int j = 0; j < 4; ++j) {
            float v_[4];
            float vmax = -INFINITY;
            #pragma unroll
            for (int n = 0; n < 4; ++n) {
                const int gcol = v0 + wc * 64 + n * 16 + lo4;
                const float v  = acc[m][n][j];
                v_[n] = (gcol < V_DIM) ? v : -INFINITY;
                vmax = fmaxf(vmax, v_[n]);
            }
            #pragma unroll
            for (int d = 1; d < 16; d <<= 1)
                vmax = fmaxf(vmax, __shfl_xor(vmax, d, 64));
            float s = 0.f;
            if (vmax > -INFINITY) {
                #pragma unroll
                for (int n = 0; n < 4; ++n) s += __expf(v_[n] - vmax);
                #pragma unroll
                for (int d = 1; d < 16; d <<= 1)
                    s += __shfl_xor(s, d, 64);
            }
            if (lo4 == 0) {
                const int row = wr * 128 + m * 16 + hi2 * 4 + j;
                scrM[row * 4 + wc] = vmax;
                scrS[row * 4 + wc] = s;
            }
        }
    }
    __syncthreads();
    if (tid < 256) {
        float M = -INFINITY;
        #pragma unroll
        for (int w4 = 0; w4 < 4; ++w4) M = fmaxf(M, scrM[tid * 4 + w4]);
        float S = 0.f;
        #pragma unroll
        for (int w4 = 0; w4 < 4; ++w4) {
            const float mm = scrM[tid * 4 + w4];
            if (mm > -INFINITY) S += scrS[tid * 4 + w4] * __expf(mm - M);
        }
        const size_t idx = (size_t)vb * M_TOTAL + m0 + tid;
        pm[idx] = M;
        ps[idx] = S;
    }
}

// ---------------- picked logit from EXACT fp32 inputs ----------------------
__global__ __launch_bounds__(256)
void lce_picked_f32(const float* __restrict__ x, const float* __restrict__ w,
                    const int* __restrict__ labels, float* __restrict__ picked)
{
    const int wv  = threadIdx.x >> 6, ln = threadIdx.x & 63;
    const int row = blockIdx.x * 4 + wv;
    const int lbl = labels[row];
    float s = 0.f;
    if (lbl != IGNORE_IDX) {
        const float* xr = x + (size_t)row * K_DIM;
        const float* wr = w + (size_t)lbl * K_DIM;
        #pragma unroll
        for (int c = 0; c < 8; ++c) {
            const f32x4 a = *(const f32x4*)(xr + c * 256 + ln * 4);
            const f32x4 b = *(const f32x4*)(wr + c * 256 + ln * 4);
            s += a.x * b.x + a.y * b.y + a.z * b.z + a.w * b.w;
        }
    }
    #pragma unroll
    for (int d = 32; d; d >>= 1) s += __shfl_down(s, d, 64);
    if (ln == 0) picked[row] = s;
}

// ---------------- chunk-combine + finalize ---------------------------------
__global__ __launch_bounds__(256)
void lce_row_reduce(const float* __restrict__ pm, const float* __restrict__ ps,
                    const float* __restrict__ picked, const int* __restrict__ labels,
                    float* __restrict__ pb)
{
    const int r   = blockIdx.x * 256 + threadIdx.x;
    const int lbl = labels[r];
    float nll = 0.f, zsq = 0.f, val = 0.f;
    if (lbl != IGNORE_IDX) {
        float M = -INFINITY;
        for (int c = 0; c < NVB; ++c)
            M = fmaxf(M, pm[(size_t)c * M_TOTAL + r]);
        float S = 0.f;
        for (int c = 0; c < NVB; ++c) {
            const float mc = pm[(size_t)c * M_TOTAL + r];
            if (mc > -INFINITY) S += ps[(size_t)c * M_TOTAL + r] * expf(mc - M);
        }
        const float lse = M + logf(S);
        nll = lse - picked[r];
        zsq = lse * lse;
        val = 1.f;
    }
    #pragma unroll
    for (int d = 32; d; d >>= 1) {
        nll += __shfl_down(nll, d, 64);
        zsq += __shfl_down(zsq, d, 64);
        val += __shfl_down(val, d, 64);
    }
    __shared__ float red[3][4];
    const int wv = threadIdx.x >> 6, ln = threadIdx.x & 63;
    if (ln == 0) { red[0][wv] = nll; red[1][wv] = zsq; red[2][wv] = val; }
    __syncthreads();
    if (threadIdx.x == 0) {
        float a = 0.f, b = 0.f, c_ = 0.f;
        #pragma unroll
        for (int i = 0; i < 4; ++i) { a += red[0][i]; b += red[1][i]; c_ += red[2][i]; }
        pb[blockIdx.x * 3 + 0] = a;
        pb[blockIdx.x * 3 + 1] = b;
        pb[blockIdx.x * 3 + 2] = c_;
    }
}

__global__ void lce_finalize(const float* __restrict__ pb, float* __restrict__ out)
{
    float a = 0.f, b = 0.f, c_ = 0.f;
    for (int i = 0; i < 16; ++i) {
        a  += pb[i * 3 + 0];
        b  += pb[i * 3 + 1];
        c_ += pb[i * 3 + 2];
    }
    const float denom = fmaxf(c_, 1.f);
    float loss = a / denom;
    if (c_ > 0.f) loss += Z_REG * (b / denom);
    out[0] = loss;
}

// ---------------- fallback fused fp32 path (round-0 kernel, tiny ws) -------
#define FVC 1024
#define FNCHUNK 50
#define FBK 64
#define LDSPAD 72
__device__ inline bf16x4 cvt4(f32x4 v) {
    bf16x4 r;
    r.x = (bf16_t)v.x; r.y = (bf16_t)v.y; r.z = (bf16_t)v.z; r.w = (bf16_t)v.w;
    return r;
}
__global__ __launch_bounds__(256)
void lce_gemm_stats_fused(const float* __restrict__ X, const float* __restrict__ W,
                          const int* __restrict__ labels,
                          float* __restrict__ pm, float* __restrict__ ps,
                          float* __restrict__ pp)
{
    __shared__ bf16_t As[128][LDSPAD];
    __shared__ bf16_t Bsh[128][LDSPAD];
    __shared__ float  sm[128], ss[128], sp[128];
    __shared__ float  part_m[2][128], part_s[2][128];
    __shared__ int    slab[128];

    const int bx    = blockIdx.x;
    const int chunk = bx >> 5;
    const int mb    = bx & 31;
    const int m0    = mb * 128;
    const int v0    = chunk * FVC;
    const int tid   = threadIdx.x;
    const int lane  = tid & 63;
    const int wave  = tid >> 6;
    const int wr    = wave >> 1;
    const int wc    = wave & 1;
    const int lo4   = lane & 15;
    const int hi2   = lane >> 4;
    const int sr0   = tid >> 4;
    const int sc4   = tid & 15;

    if (tid < 128) {
        sm[tid] = -INFINITY; ss[tid] = 0.f; sp[tid] = 0.f;
        slab[tid] = labels[m0 + tid];
    }
    __syncthreads();

    const int ncols = min(FVC, V_DIM - v0);
    const int nt    = (ncols + 127) >> 7;

    for (int vt = 0; vt < nt; ++vt) {
        f32x4 acc[4][4];
        #pragma unroll
        for (int m = 0; m < 4; ++m)
            #pragma unroll
            for (int n = 0; n < 4; ++n) {
                f32x4 z = {0.f, 0.f, 0.f, 0.f};
                acc[m][n] = z;
            }
        const int vrow0 = v0 + vt * 128;
        for (int kt = 0; kt < K_DIM / FBK; ++kt) {
            #pragma unroll
            for (int i = 0; i < 8; ++i) {
                const int row = i * 16 + sr0;
                const f32x4 va = *(const f32x4*)(X + (size_t)(m0 + row) * K_DIM + kt * FBK + sc4 * 4);
                *(bf16x4*)&As[row][sc4 * 4] = cvt4(va);
                const int grow = vrow0 + row;
                f32x4 vb = {0.f, 0.f, 0.f, 0.f};
                if (grow < V_DIM)
                    vb = *(const f32x4*)(W + (size_t)grow * K_DIM + kt * FBK + sc4 * 4);
                *(bf16x4*)&Bsh[row][sc4 * 4] = cvt4(vb);
            }
            __syncthreads();
            #pragma unroll
            for (int ks = 0; ks < 2; ++ks) {
                bf16x8 af[4], bfr[4];
                #pragma unroll
                for (int m = 0; m < 4; ++m)
                    af[m] = *(const bf16x8*)&As[wr * 64 + m * 16 + lo4][ks * 32 + hi2 * 8];
                #pragma unroll
                for (int n = 0; n < 4; ++n)
                    bfr[n] = *(const bf16x8*)&Bsh[wc * 64 + n * 16 + lo4][ks * 32 + hi2 * 8];
                #pragma unroll
                for (int m = 0; m < 4; ++m)
                    #pragma unroll
                    for (int n = 0; n < 4; ++n)
                        acc[m][n] = __builtin_amdgcn_mfma_f32_16x16x32_bf16(af[m], bfr[n], acc[m][n], 0, 0, 0);
            }
            __syncthreads();
        }
        const int vbase = vrow0 + wc * 64;
        #pragma unroll
        for (int m = 0; m < 4; ++m) {
            #pragma unroll
            for (int j = 0; j < 4; ++j) {
                const int rloc = wr * 64 + m * 16 + hi2 * 4 + j;
                const int lb   = slab[rloc];
                float vmax = -INFINITY;
                float v_[4];
                #pragma unroll
                for (int n = 0; n < 4; ++n) {
                    const int gcol = vbase + n * 16 + lo4;
                    const float v  = acc[m][n][j];
                    const bool ok  = (gcol < V_DIM);
                    v_[n] = ok ? v : -INFINITY;
                    if (ok && gcol == lb) sp[rloc] = v;
                    vmax = fmaxf(vmax, v_[n]);
                }
                #pragma unroll
                for (int d = 1; d < 16; d <<= 1)
                    vmax = fmaxf(vmax, __shfl_xor(vmax, d, 64));
                float s = 0.f;
                #pragma unroll
                for (int n = 0; n < 4; ++n) s += __expf(v_[n] - vmax);
                #pragma unroll
                for (int d = 1; d < 16; d <<= 1) s += __shfl_xor(s, d, 64);
                if (lo4 == 0) { part_m[wc][rloc] = vmax; part_s[wc][rloc] = s; }
            }
        }
        __syncthreads();
        if (tid < 128) {
            const float om  = sm[tid], os = ss[tid];
            const float m0_ = part_m[0][tid], s0 = part_s[0][tid];
            const float m1_ = part_m[1][tid], s1 = part_s[1][tid];
            const float nm  = fmaxf(om, fmaxf(m0_, m1_));
            float ns = 0.f;
            if (om  > -INFINITY) ns += os * __expf(om  - nm);
            if (m0_ > -INFINITY) ns += s0 * __expf(m0_ - nm);
            if (m1_ > -INFINITY) ns += s1 * __expf(m1_ - nm);
            sm[tid] = nm; ss[tid] = ns;
        }
    }
    __syncthreads();
    if (tid < 128) {
        const size_t idx = (size_t)chunk * M_TOTAL + (m0 + tid);
        pm[idx] = sm[tid]; ps[idx] = ss[tid]; pp[idx] = sp[tid];
    }
}

__global__ __launch_bounds__(256)
void lce_row_reduce_f(const float* __restrict__ pm, const float* __restrict__ ps,
                      const float* __restrict__ pp, const int* __restrict__ labels,
                      float* __restrict__ pb)
{
    const int r   = blockIdx.x * 256 + threadIdx.x;
    const int lbl = labels[r];
    float nll = 0.f, zsq = 0.f, val = 0.f;
    if (lbl != IGNORE_IDX) {
        float M = -INFINITY;
        for (int c = 0; c < FNCHUNK; ++c)
            M = fmaxf(M, pm[(size_t)c * M_TOTAL + r]);
        float S = 0.f, P = 0.f;
        for (int c = 0; c < FNCHUNK; ++c) {
            const float mc = pm[(size_t)c * M_TOTAL + r];
            if (mc > -INFINITY) S += ps[(size_t)c * M_TOTAL + r] * expf(mc - M);
            P += pp[(size_t)c * M_TOTAL + r];
        }
        const float lse = M + logf(S);
        nll = lse - P; zsq = lse * lse; val = 1.f;
    }
    #pragma unroll
    for (int d = 32; d; d >>= 1) {
        nll += __shfl_down(nll, d, 64);
        zsq += __shfl_down(zsq, d, 64);
        val += __shfl_down(val, d, 64);
    }
    __shared__ float red[3][4];
    const int wv = threadIdx.x >> 6, ln = threadIdx.x & 63;
    if (ln == 0) { red[0][wv] = nll; red[1][wv] = zsq; red[2][wv] = val; }
    __syncthreads();
    if (threadIdx.x == 0) {
        float a = 0.f, b = 0.f, c_ = 0.f;
        #pragma unroll
        for (int i = 0; i < 4; ++i) { a += red[0][i]; b += red[1][i]; c_ += red[2][i]; }
        pb[blockIdx.x * 3 + 0] = a;
        pb[blockIdx.x * 3 + 1] = b;
        pb[blockIdx.x * 3 + 2] = c_;
    }
}

extern "C" void kernel_launch(void* const* d_in, const int* in_sizes, int n_in,
                              void* d_out, int out_size, void* d_ws, size_t ws_size,
                              hipStream_t stream)
{
    const float* x      = (const float*)d_in[0];
    const int*   labels = (const int*)d_in[1];
    const float* w      = (const float*)d_in[2];
    float*       out    = (float*)d_out;

    const size_t wq_b   = (size_t)V_PAD * K_DIM;        // 103,284,736
    const size_t xq_b   = (size_t)M_TOTAL * K_DIM;      //   8,388,608
    const size_t sbt_b  = (size_t)NKB * V_PAD;          //   3,227,648
    const size_t sat_b  = (size_t)NKB * M_TOTAL;        //     262,144
    const size_t stat_n = (size_t)NVB * M_TOTAL;        //     806,912

    size_t off = 0;
    auto take = [&](size_t bytes) { size_t o = off; off += (bytes + 255) & ~(size_t)255; return o; };
    const size_t o_wq  = take(wq_b);
    const size_t o_xq  = take(xq_b);
    const size_t o_sbt = take(sbt_b);
    const size_t o_sat = take(sat_b);
    const size_t o_pm  = take(stat_n * sizeof(float));
    const size_t o_ps  = take(stat_n * sizeof(float));
    const size_t o_pk  = take(M_TOTAL * sizeof(float));
    const size_t o_pb  = take(16 * 3 * sizeof(float));
    const size_t need  = off;

    if (ws_size >= need) {
        uint8_t* Wq  = (uint8_t*)d_ws + o_wq;
        uint8_t* Xq  = (uint8_t*)d_ws + o_xq;
        uint8_t* sBT = (uint8_t*)d_ws + o_sbt;
        uint8_t* sAT = (uint8_t*)d_ws + o_sat;
        float* pm     = (float*)((char*)d_ws + o_pm);
        float* ps     = (float*)((char*)d_ws + o_ps);
        float* picked = (float*)((char*)d_ws + o_pk);
        float* pb     = (float*)((char*)d_ws + o_pb);

        cvt_f32_fp8mx<6><<<dim3(4096), dim3(256), 0, stream>>>(w, Wq, sBT, V_DIM, V_PAD);
        cvt_f32_fp8mx<7><<<dim3(1024), dim3(256), 0, stream>>>(x, Xq, sAT, M_TOTAL, M_TOTAL);
        lce_gemm_fp8<<<dim3(NWG), dim3(512), 0, stream>>>(Xq, Wq, sAT, sBT, pm, ps);
        lce_picked_f32<<<dim3(1024), dim3(256), 0, stream>>>(x, w, labels, picked);
        lce_row_reduce<<<dim3(16), dim3(256), 0, stream>>>(pm, ps, picked, labels, pb);
        lce_finalize<<<dim3(1), dim3(1), 0, stream>>>(pb, out);
    } else {
        const size_t fstat_n = (size_t)FNCHUNK * M_TOTAL;
        float* pm = (float*)d_ws;
        float* ps = pm + fstat_n;
        float* pp = ps + fstat_n;
        float* pb = pp + fstat_n;
        lce_gemm_stats_fused<<<dim3(FNCHUNK * 32), dim3(256), 0, stream>>>(
            x, w, labels, pm, ps, pp);
        lce_row_reduce_f<<<dim3(16), dim3(256), 0, stream>>>(pm, ps, pp, labels, pb);
        lce_finalize<<<dim3(1), dim3(1), 0, stream>>>(pb, out);
    }
}